// Round 12
// baseline (185.014 us; speedup 1.0000x reference)
//
#include <hip/hip_runtime.h>
#include <stdint.h>

// Problem constants
constexpr int C_IN  = 512;
constexpr int HW    = 784;            // 28*28
constexpr int NB    = 32;
constexpr int M_TOT = NB * HW;        // 25088 = 98*256
constexpr int N_TOT = 2000;
constexpr int NPAD  = 2048;
constexpr int IMG_STRIDE = C_IN * HW;
constexpr int OUT_BATCH  = N_TOT * HW;

// GEMM tiling: 256x128 block, 4 waves (wave 128x64), BK=32, NO LDS:
// fragments stream straight from L2 (both matrices k-major) with a
// register double-buffer; no barriers, waves fully independent.
constexpr int TBM = 256;
constexpr int TBN = 128;
constexpr int NKT = C_IN / 32;        // 16

constexpr int PREPA_BLOCKS = M_TOT / 64;   // 392
constexpr int PREPW_BLOCKS = NPAD / 4;     // 512

typedef __attribute__((ext_vector_type(8))) short bf16x8;
typedef __attribute__((ext_vector_type(4))) float f32x4;

__device__ __forceinline__ uint16_t f2bf(float f) {
    union { float f; uint32_t u; } x; x.f = f;
    return (uint16_t)((x.u + 0x8000u) >> 16);
}

// non-temporal 16B load/store via clang ext_vector (HIP float4 is rejected)
__device__ __forceinline__ f32x4 nt_load4(const float* p) {
    return __builtin_nontemporal_load((const f32x4*)p);
}
__device__ __forceinline__ void nt_store4(float* p, f32x4 v) {
    __builtin_nontemporal_store(v, (f32x4*)p);
}

// ---------------------------------------------------------------------------
// prep: blocks [0,392): Abf[m][k] = bf16(input) transposed via LDS, fused s2[m]
//       blocks [392,904): Wbf[p][k] = bf16(w) (rows >= N_TOT zeroed), fused w2[p]
__global__ __launch_bounds__(256) void prep_kernel(const float* __restrict__ in,
                                                   const float* __restrict__ w,
                                                   short* __restrict__ Abf,
                                                   short* __restrict__ Wbf,
                                                   float* __restrict__ s2,
                                                   float* __restrict__ w2) {
    __shared__ __align__(16) char T[64 * 512 * 2];
    __shared__ float red[16][64];

    const int t = threadIdx.x;

    if (blockIdx.x >= PREPA_BLOCKS) {
        const int wv = t >> 6, lane = t & 63;
        const int p = (blockIdx.x - PREPA_BLOCKS) * 4 + wv;
        bf16x8 o = (bf16x8)0;
        float s = 0.f;
        if (p < N_TOT) {
            const float* base = w + (size_t)p * C_IN + lane * 8;
            f32x4 a = nt_load4(base);
            f32x4 c = nt_load4(base + 4);
            s = a[0]*a[0] + a[1]*a[1] + a[2]*a[2] + a[3]*a[3]
              + c[0]*c[0] + c[1]*c[1] + c[2]*c[2] + c[3]*c[3];
            o[0] = (short)f2bf(a[0]); o[1] = (short)f2bf(a[1]);
            o[2] = (short)f2bf(a[2]); o[3] = (short)f2bf(a[3]);
            o[4] = (short)f2bf(c[0]); o[5] = (short)f2bf(c[1]);
            o[6] = (short)f2bf(c[2]); o[7] = (short)f2bf(c[3]);
        }
        *(bf16x8*)(Wbf + (size_t)p * C_IN + lane * 8) = o;
#pragma unroll
        for (int off = 32; off; off >>= 1) s += __shfl_down(s, off);
        if (lane == 0) w2[p] = s;
        return;
    }

    const int q = t & 15;
    const int part = t >> 4;
    const int m0q = blockIdx.x * 64 + q * 4;
    const uint32_t b  = (uint32_t)m0q / 784u;
    const uint32_t hw = (uint32_t)m0q % 784u;
    const float* base = in + (size_t)b * IMG_STRIDE + hw;

    float acx = 0.f, acy = 0.f, acz = 0.f, acw = 0.f;
    const int c0 = part * 32;
#pragma unroll 4
    for (int c = c0; c < c0 + 32; ++c) {
        f32x4 v = nt_load4(base + (size_t)c * HW);
        acx = fmaf(v[0], v[0], acx);
        acy = fmaf(v[1], v[1], acy);
        acz = fmaf(v[2], v[2], acz);
        acw = fmaf(v[3], v[3], acw);
        uint16_t vals[4] = { f2bf(v[0]), f2bf(v[1]), f2bf(v[2]), f2bf(v[3]) };
        const uint32_t by0 = (uint32_t)(q * 4) * 1024u + (uint32_t)c * 2u;
#pragma unroll
        for (int j = 0; j < 4; ++j) {
            uint32_t bb = by0 + (uint32_t)j * 1024u;
            bb ^= ((bb >> 12) & 7u) << 4;
            *(uint16_t*)(T + bb) = vals[j];
        }
    }
    red[part][q * 4 + 0] = acx;
    red[part][q * 4 + 1] = acy;
    red[part][q * 4 + 2] = acz;
    red[part][q * 4 + 3] = acw;
    __syncthreads();
    if (t < 64) {
        float s = 0.f;
#pragma unroll
        for (int p = 0; p < 16; ++p) s += red[p][t];
        s2[blockIdx.x * 64 + t] = s;
    }
    short* dst = Abf + (size_t)blockIdx.x * 64 * 512;
#pragma unroll
    for (int i = 0; i < 16; ++i) {
        const int idx = i * 256 + t;
        const int row = idx >> 6, ch = idx & 63;
        uint32_t bb = (uint32_t)row * 1024u + (uint32_t)ch * 16u;
        bb ^= ((bb >> 12) & 7u) << 4;
        bf16x8 v = *(bf16x8*)(T + bb);
        *(bf16x8*)(dst + (size_t)row * 512 + ch * 8) = v;
    }
}

// ---------------------------------------------------------------------------
// gemm11: ZERO-LDS fragment-streaming GEMM.
//   Both Abf and Wbf are k-major -> each MFMA fragment is a direct contiguous
//   16 B global load (L2-resident panels: A 256 KB/bm shared by 16 blocks,
//   B 2 MB total, bn-fast grid keeps both hot per XCD; L1 catches the 2-wave
//   row duplication inside a block). Register double-buffer, prefetch depth 2;
//   no barriers -- each wave stalls only on its own (compiler-counted) vmcnt.
//   4 waves/block, wave owns 128m x 64n (acc[8][4] = 128 VGPR; ~235 total).
__global__ __launch_bounds__(256, 2) void gemm11_kernel(const short* __restrict__ Abf,
                                                        const short* __restrict__ Wbf,
                                                        const float* __restrict__ s2,
                                                        const float* __restrict__ w2,
                                                        float* __restrict__ out) {
    const int t = threadIdx.x;
    const int wv = t >> 6, lane = t & 63;
    const int lr = lane & 15, lg = lane >> 4;

    const int bid = blockIdx.x;
    const int bn = bid & 15;     // fast: 16 consecutive blocks share one A panel
    const int bm = bid >> 4;

    // wave -> output subtile (128m x 64n)
    const int wm = (wv >> 1) * 128;        // {0,128}
    const int wn = (wv & 1) * 64;          // {0,64}

    // per-lane fragment bases (k-major; fragment = 16 B contiguous at k-offset)
    const short* Arow = Abf + (size_t)(bm * TBM + wm + lr) * C_IN + lg * 8;
    const short* Brow = Wbf + (size_t)(bn * TBN + wn + lr) * C_IN + lg * 8;

    bf16x8 a0[8], b0[4], a1[8], b1[4];
    f32x4 acc[8][4] = {};

#define LOADF(kt, aa, bb)                                                      \
    do {                                                                       \
        _Pragma("unroll") for (int m = 0; m < 8; ++m)                          \
            aa[m] = *(const bf16x8*)(Arow + (size_t)m * 16 * C_IN + (kt) * 32);\
        _Pragma("unroll") for (int n = 0; n < 4; ++n)                          \
            bb[n] = *(const bf16x8*)(Brow + (size_t)n * 16 * C_IN + (kt) * 32);\
    } while (0)

#define COMPUTE(aa, bb)                                                        \
    do {                                                                       \
        __builtin_amdgcn_s_setprio(1);                                         \
        _Pragma("unroll") for (int m = 0; m < 8; ++m)                          \
            _Pragma("unroll") for (int n = 0; n < 4; ++n)                      \
                acc[m][n] = __builtin_amdgcn_mfma_f32_16x16x32_bf16(           \
                    aa[m], bb[n], acc[m][n], 0, 0, 0);                         \
        __builtin_amdgcn_s_setprio(0);                                         \
    } while (0)

    LOADF(0, a0, b0);
    LOADF(1, a1, b1);

#pragma unroll
    for (int kt = 0; kt < NKT; ++kt) {
        if ((kt & 1) == 0) {
            COMPUTE(a0, b0);                       // waits only on a0/b0 regs
            if (kt + 2 < NKT) LOADF(kt + 2, a0, b0);   // refill after last read
        } else {
            COMPUTE(a1, b1);
            if (kt + 2 < NKT) LOADF(kt + 2, a1, b1);
        }
    }
#undef LOADF
#undef COMPUTE

    // epilogue: relu(s2 - 2*acc + w2), non-temporal f32x4 stores (bypass L3)
    float wreg[4];
    int n_ok[4];
#pragma unroll
    for (int n = 0; n < 4; ++n) {
        const int n_o = bn * TBN + wn + n * 16 + lr;
        n_ok[n] = (n_o < N_TOT);
        wreg[n] = n_ok[n] ? w2[n_o] : 0.f;
    }
#pragma unroll
    for (int m = 0; m < 8; ++m) {
        const int m_r = bm * TBM + wm + m * 16 + lg * 4;   // 4-aligned, 784%4==0
        const f32x4 s2v = *(const f32x4*)(s2 + m_r);
        const uint32_t ob  = (uint32_t)m_r / 784u;
        const uint32_t ohw = (uint32_t)m_r % 784u;
        float* obase = out + (size_t)ob * OUT_BATCH + ohw;
#pragma unroll
        for (int n = 0; n < 4; ++n) {
            if (n_ok[n]) {
                const int n_o = bn * TBN + wn + n * 16 + lr;
                const f32x4 a = acc[m][n];
                f32x4 r;
                r[0] = fmaxf(s2v[0] - 2.f * a[0] + wreg[n], 0.f);
                r[1] = fmaxf(s2v[1] - 2.f * a[1] + wreg[n], 0.f);
                r[2] = fmaxf(s2v[2] - 2.f * a[2] + wreg[n], 0.f);
                r[3] = fmaxf(s2v[3] - 2.f * a[3] + wreg[n], 0.f);
                nt_store4(obase + (size_t)n_o * HW, r);
            }
        }
    }
}

// ---------------------------------------------------------------------------
extern "C" void kernel_launch(void* const* d_in, const int* in_sizes, int n_in,
                              void* d_out, int out_size, void* d_ws, size_t ws_size,
                              hipStream_t stream) {
    const float* in = (const float*)d_in[0];   // [32,512,28,28] fp32
    const float* w  = (const float*)d_in[1];   // [2000,512,1,1] fp32
    float* out = (float*)d_out;                // [32,2000,28,28] fp32

    const size_t offA  = 0;
    const size_t offW  = offA + (size_t)M_TOT * C_IN * sizeof(short);   // 25.7 MB
    const size_t offS2 = offW + (size_t)NPAD * C_IN * sizeof(short);    // +2.1 MB
    const size_t offW2 = offS2 + (size_t)M_TOT * sizeof(float);

    short* Abf = (short*)((char*)d_ws + offA);
    short* Wbf = (short*)((char*)d_ws + offW);
    float* s2  = (float*)((char*)d_ws + offS2);
    float* w2  = (float*)((char*)d_ws + offW2);

    prep_kernel<<<PREPA_BLOCKS + PREPW_BLOCKS, 256, 0, stream>>>(in, w, Abf, Wbf, s2, w2);

    // 98 m-tiles x 16 n-tiles = 1568 blocks, 2 resident per CU, no barriers
    gemm11_kernel<<<98 * 16, 256, 0, stream>>>(Abf, Wbf, s2, w2, out);
}

// Round 13
// 149.291 us; speedup vs baseline: 1.2393x; 1.2393x over previous
//
#include <hip/hip_runtime.h>
#include <stdint.h>

// Problem constants
constexpr int C_IN  = 512;
constexpr int HW    = 784;            // 28*28
constexpr int NB    = 32;
constexpr int M_TOT = NB * HW;        // 25088 = 98*256
constexpr int N_TOT = 2000;
constexpr int NPAD  = 2048;
constexpr int IMG_STRIDE = C_IN * HW;
constexpr int OUT_BATCH  = N_TOT * HW;

// GEMM: 256x128 block, 4 waves (wave 128x64), BK=32, ZERO-LDS fragment
// streaming from a FRAGMENT-MAJOR workspace layout (every MFMA fragment is a
// contiguous, aligned 1 KB wave-load). No barriers. Register double-buffer.
constexpr int TBM = 256;
constexpr int TBN = 128;
constexpr int NKT = C_IN / 32;        // 16

constexpr int PREPA_BLOCKS = M_TOT / 64;   // 392 (64 rows = 4 mtiles each)
constexpr int PREPW_BLOCKS = NPAD / 16;    // 128 (16 rows = 1 ntile each)

typedef __attribute__((ext_vector_type(8))) short bf16x8;
typedef __attribute__((ext_vector_type(4))) float f32x4;

__device__ __forceinline__ uint16_t f2bf(float f) {
    union { float f; uint32_t u; } x; x.f = f;
    return (uint16_t)((x.u + 0x8000u) >> 16);
}

// non-temporal 16B load/store via clang ext_vector
__device__ __forceinline__ f32x4 nt_load4(const float* p) {
    return __builtin_nontemporal_load((const f32x4*)p);
}
__device__ __forceinline__ void nt_store4(float* p, f32x4 v) {
    __builtin_nontemporal_store(v, (f32x4*)p);
}

// ---------------------------------------------------------------------------
// prep: blocks [0,392): A -> fragment-major bf16 (Afr), fused s2
//       blocks [392,520): W -> fragment-major bf16 (Wfr, rows>=N_TOT zero), w2
// Fragment layout: frag index fi = mtile*16 + kt  (mtile = row/16, kt = k/32);
//   Afr[fi*64 + lane] (16 B) = A[mtile*16 + (lane&15)][kt*32 + (lane>>4)*8 ..+7]
// so a wave's MFMA fragment load is contiguous 1 KB. Same for Wfr.
__global__ __launch_bounds__(256) void prep_kernel(const float* __restrict__ in,
                                                   const float* __restrict__ w,
                                                   short* __restrict__ Afr,
                                                   short* __restrict__ Wfr,
                                                   float* __restrict__ s2,
                                                   float* __restrict__ w2) {
    __shared__ __align__(16) char T[64 * 512 * 2];
    __shared__ float red[16][64];

    const int t = threadIdx.x;
    const int wvl = t >> 6, l = t & 63;

    if (blockIdx.x >= PREPA_BLOCKS) {
        // ---------------- prep_w: one ntile (16 rows) per block ----------------
        const int b = blockIdx.x - PREPA_BLOCKS;   // 0..127
        const int r = t >> 4;                      // row in tile 0..15
        const int c = t & 15;                      // k-chunk of 32
        const int p = b * 16 + r;
        float s = 0.f;
        if (p < N_TOT) {
            const float* base = w + (size_t)p * C_IN + c * 32;
#pragma unroll
            for (int j = 0; j < 4; ++j) {
                f32x4 x = nt_load4(base + j * 8);
                f32x4 y = nt_load4(base + j * 8 + 4);
                s += x[0]*x[0] + x[1]*x[1] + x[2]*x[2] + x[3]*x[3]
                   + y[0]*y[0] + y[1]*y[1] + y[2]*y[2] + y[3]*y[3];
                bf16x8 o;
                o[0] = (short)f2bf(x[0]); o[1] = (short)f2bf(x[1]);
                o[2] = (short)f2bf(x[2]); o[3] = (short)f2bf(x[3]);
                o[4] = (short)f2bf(y[0]); o[5] = (short)f2bf(y[1]);
                o[6] = (short)f2bf(y[2]); o[7] = (short)f2bf(y[3]);
                const int ch = c * 4 + j;
                uint32_t bb = (uint32_t)r * 1024u + (uint32_t)ch * 16u;
                bb ^= ((bb >> 12) & 7u) << 4;
                *(bf16x8*)(T + bb) = o;
            }
        } else {
            bf16x8 z = (bf16x8)0;
#pragma unroll
            for (int j = 0; j < 4; ++j) {
                const int ch = c * 4 + j;
                uint32_t bb = (uint32_t)r * 1024u + (uint32_t)ch * 16u;
                bb ^= ((bb >> 12) & 7u) << 4;
                *(bf16x8*)(T + bb) = z;
            }
        }
        red[r][c] = s;
        __syncthreads();
        if (t < 16) {
            float ss = 0.f;
#pragma unroll
            for (int c2 = 0; c2 < 16; ++c2) ss += red[t][c2];
            w2[b * 16 + t] = ss;
        }
        // fragment writes: 16 kt-fragments; 4 iters x 4 waves, 1 KB each
        short* dstW = Wfr + (size_t)b * 16 * 512;
#pragma unroll
        for (int i = 0; i < 4; ++i) {
            const int kt = i * 4 + wvl;
            const int row = l & 15;
            const int ch  = kt * 4 + (l >> 4);
            uint32_t bb = (uint32_t)row * 1024u + (uint32_t)ch * 16u;
            bb ^= ((bb >> 12) & 7u) << 4;
            bf16x8 v = *(bf16x8*)(T + bb);
            *(bf16x8*)(dstW + (size_t)kt * 512 + l * 8) = v;
        }
        return;
    }

    // ---------------- prep_a: 64 rows (4 mtiles) per block ----------------
    const int q = t & 15;
    const int part = t >> 4;
    const int m0q = blockIdx.x * 64 + q * 4;
    const uint32_t b  = (uint32_t)m0q / 784u;
    const uint32_t hw = (uint32_t)m0q % 784u;
    const float* base = in + (size_t)b * IMG_STRIDE + hw;

    float acx = 0.f, acy = 0.f, acz = 0.f, acw = 0.f;
    const int c0 = part * 32;
#pragma unroll 4
    for (int c = c0; c < c0 + 32; ++c) {
        f32x4 v = nt_load4(base + (size_t)c * HW);
        acx = fmaf(v[0], v[0], acx);
        acy = fmaf(v[1], v[1], acy);
        acz = fmaf(v[2], v[2], acz);
        acw = fmaf(v[3], v[3], acw);
        uint16_t vals[4] = { f2bf(v[0]), f2bf(v[1]), f2bf(v[2]), f2bf(v[3]) };
        const uint32_t by0 = (uint32_t)(q * 4) * 1024u + (uint32_t)c * 2u;
#pragma unroll
        for (int j = 0; j < 4; ++j) {
            uint32_t bb = by0 + (uint32_t)j * 1024u;
            bb ^= ((bb >> 12) & 7u) << 4;
            *(uint16_t*)(T + bb) = vals[j];
        }
    }
    red[part][q * 4 + 0] = acx;
    red[part][q * 4 + 1] = acy;
    red[part][q * 4 + 2] = acz;
    red[part][q * 4 + 3] = acw;
    __syncthreads();
    if (t < 64) {
        float s = 0.f;
#pragma unroll
        for (int p = 0; p < 16; ++p) s += red[p][t];
        s2[blockIdx.x * 64 + t] = s;
    }
    // fragment writes: 4 mtiles x 16 kt = 64 fragments; 16 iters x 4 waves
    short* dstA = Afr + (size_t)blockIdx.x * 64 * 512;
#pragma unroll
    for (int i = 0; i < 16; ++i) {
        const int f = i * 4 + wvl;            // 0..63
        const int mtile = f >> 4;             // 0..3
        const int kt    = f & 15;             // 0..15
        const int row = mtile * 16 + (l & 15);
        const int ch  = kt * 4 + (l >> 4);
        uint32_t bb = (uint32_t)row * 1024u + (uint32_t)ch * 16u;
        bb ^= ((bb >> 12) & 7u) << 4;
        bf16x8 v = *(bf16x8*)(T + bb);
        *(bf16x8*)(dstA + (size_t)(mtile * 16 + kt) * 512 + l * 8) = v;
    }
}

// ---------------------------------------------------------------------------
// gemm12: zero-LDS, barrier-free fragment-streaming GEMM over fragment-major
// layout. Every fragment load = contiguous aligned 1 KB wave-load from L2/L3.
// Register double-buffer, prefetch depth 2; waves fully independent.
__global__ __launch_bounds__(256, 2) void gemm12_kernel(const short* __restrict__ Afr,
                                                        const short* __restrict__ Wfr,
                                                        const float* __restrict__ s2,
                                                        const float* __restrict__ w2,
                                                        float* __restrict__ out) {
    const int t = threadIdx.x;
    const int wv = t >> 6, lane = t & 63;
    const int lr = lane & 15, lg = lane >> 4;

    const int bid = blockIdx.x;
    const int bn = bid & 15;     // fast: 16 consecutive blocks share one A panel
    const int bm = bid >> 4;

    const int wm = (wv >> 1) * 128;        // {0,128}
    const int wn = (wv & 1) * 64;          // {0,64}

    // fragment bases: frag (m, kt) at  base + m*8192 + kt*512  (shorts)
    const short* Ab = Afr + (size_t)(bm * 16 + (wm >> 4)) * 8192 + lane * 8;
    const short* Bb = Wfr + (size_t)(bn * 8 + (wn >> 4)) * 8192 + lane * 8;

    bf16x8 a0[8], b0[4], a1[8], b1[4];
    f32x4 acc[8][4] = {};

#define LOADF(kt, aa, bb)                                                      \
    do {                                                                       \
        _Pragma("unroll") for (int m = 0; m < 8; ++m)                          \
            aa[m] = *(const bf16x8*)(Ab + (size_t)m * 8192 + (kt) * 512);      \
        _Pragma("unroll") for (int n = 0; n < 4; ++n)                          \
            bb[n] = *(const bf16x8*)(Bb + (size_t)n * 8192 + (kt) * 512);      \
    } while (0)

#define COMPUTE(aa, bb)                                                        \
    do {                                                                       \
        __builtin_amdgcn_s_setprio(1);                                         \
        _Pragma("unroll") for (int m = 0; m < 8; ++m)                          \
            _Pragma("unroll") for (int n = 0; n < 4; ++n)                      \
                acc[m][n] = __builtin_amdgcn_mfma_f32_16x16x32_bf16(           \
                    aa[m], bb[n], acc[m][n], 0, 0, 0);                         \
        __builtin_amdgcn_s_setprio(0);                                         \
    } while (0)

    LOADF(0, a0, b0);
    LOADF(1, a1, b1);

#pragma unroll
    for (int kt = 0; kt < NKT; ++kt) {
        if ((kt & 1) == 0) {
            COMPUTE(a0, b0);
            if (kt + 2 < NKT) LOADF(kt + 2, a0, b0);
        } else {
            COMPUTE(a1, b1);
            if (kt + 2 < NKT) LOADF(kt + 2, a1, b1);
        }
    }
#undef LOADF
#undef COMPUTE

    // epilogue: relu(s2 - 2*acc + w2), non-temporal f32x4 stores
    float wreg[4];
    int n_ok[4];
#pragma unroll
    for (int n = 0; n < 4; ++n) {
        const int n_o = bn * TBN + wn + n * 16 + lr;
        n_ok[n] = (n_o < N_TOT);
        wreg[n] = n_ok[n] ? w2[n_o] : 0.f;
    }
#pragma unroll
    for (int m = 0; m < 8; ++m) {
        const int m_r = bm * TBM + wm + m * 16 + lg * 4;   // 4-aligned, 784%4==0
        const f32x4 s2v = *(const f32x4*)(s2 + m_r);
        const uint32_t ob  = (uint32_t)m_r / 784u;
        const uint32_t ohw = (uint32_t)m_r % 784u;
        float* obase = out + (size_t)ob * OUT_BATCH + ohw;
#pragma unroll
        for (int n = 0; n < 4; ++n) {
            if (n_ok[n]) {
                const int n_o = bn * TBN + wn + n * 16 + lr;
                const f32x4 a = acc[m][n];
                f32x4 r;
                r[0] = fmaxf(s2v[0] - 2.f * a[0] + wreg[n], 0.f);
                r[1] = fmaxf(s2v[1] - 2.f * a[1] + wreg[n], 0.f);
                r[2] = fmaxf(s2v[2] - 2.f * a[2] + wreg[n], 0.f);
                r[3] = fmaxf(s2v[3] - 2.f * a[3] + wreg[n], 0.f);
                nt_store4(obase + (size_t)n_o * HW, r);
            }
        }
    }
}

// ---------------------------------------------------------------------------
extern "C" void kernel_launch(void* const* d_in, const int* in_sizes, int n_in,
                              void* d_out, int out_size, void* d_ws, size_t ws_size,
                              hipStream_t stream) {
    const float* in = (const float*)d_in[0];   // [32,512,28,28] fp32
    const float* w  = (const float*)d_in[1];   // [2000,512,1,1] fp32
    float* out = (float*)d_out;                // [32,2000,28,28] fp32

    const size_t offA  = 0;
    const size_t offW  = offA + (size_t)M_TOT * C_IN * sizeof(short);   // 25.7 MB
    const size_t offS2 = offW + (size_t)NPAD * C_IN * sizeof(short);    // +2.1 MB
    const size_t offW2 = offS2 + (size_t)M_TOT * sizeof(float);

    short* Afr = (short*)((char*)d_ws + offA);
    short* Wfr = (short*)((char*)d_ws + offW);
    float* s2  = (float*)((char*)d_ws + offS2);
    float* w2  = (float*)((char*)d_ws + offW2);

    prep_kernel<<<PREPA_BLOCKS + PREPW_BLOCKS, 256, 0, stream>>>(in, w, Afr, Wfr, s2, w2);

    // 98 m-tiles x 16 n-tiles = 1568 blocks, 2/CU, no LDS, no barriers
    gemm12_kernel<<<98 * 16, 256, 0, stream>>>(Afr, Wfr, s2, w2, out);
}

// Round 14
// 94.757 us; speedup vs baseline: 1.9525x; 1.5755x over previous
//
#include <hip/hip_runtime.h>
#include <stdint.h>

// Problem constants
constexpr int C_IN  = 512;
constexpr int HW    = 784;            // 28*28
constexpr int NB    = 32;
constexpr int M_TOT = NB * HW;        // 25088 = 98*256
constexpr int N_TOT = 2000;
constexpr int NPAD  = 2048;
constexpr int IMG_STRIDE = C_IN * HW;
constexpr int OUT_BATCH  = N_TOT * HW;

// GEMM tiling: 256x128 block, 4 waves (wave 128x64), BK=32, ring-3, 2 blk/CU
constexpr int TBM = 256;
constexpr int TBN = 128;
constexpr int NKT = C_IN / 32;        // 16

constexpr int PREPA_BLOCKS = M_TOT / 64;   // 392
constexpr int PREPW_BLOCKS = NPAD / 4;     // 512

typedef __attribute__((ext_vector_type(8))) short bf16x8;
typedef __attribute__((ext_vector_type(4))) float f32x4;

__device__ __forceinline__ uint16_t f2bf(float f) {
    union { float f; uint32_t u; } x; x.f = f;
    return (uint16_t)((x.u + 0x8000u) >> 16);
}

__device__ __forceinline__ void gload_lds16(const void* g, void* l) {
    __builtin_amdgcn_global_load_lds(
        (const __attribute__((address_space(1))) void*)g,
        (__attribute__((address_space(3))) void*)l, 16, 0, 0);
}

// non-temporal 16B load (read-once input streams) — loads only; nt STORES
// measured +100 MB WRITE inflation (round 13), do not use.
__device__ __forceinline__ f32x4 nt_load4(const float* p) {
    return __builtin_nontemporal_load((const f32x4*)p);
}

// ---------------------------------------------------------------------------
// prep: blocks [0,392): Abf[m][k] = bf16(input) transposed via LDS, fused s2[m]
//       blocks [392,904): Wbf[p][k] = bf16(w) (rows >= N_TOT zeroed), fused w2[p]
__global__ __launch_bounds__(256) void prep_kernel(const float* __restrict__ in,
                                                   const float* __restrict__ w,
                                                   short* __restrict__ Abf,
                                                   short* __restrict__ Wbf,
                                                   float* __restrict__ s2,
                                                   float* __restrict__ w2) {
    __shared__ __align__(16) char T[64 * 512 * 2];
    __shared__ float red[16][64];

    const int t = threadIdx.x;

    if (blockIdx.x >= PREPA_BLOCKS) {
        const int wv = t >> 6, lane = t & 63;
        const int p = (blockIdx.x - PREPA_BLOCKS) * 4 + wv;
        bf16x8 o = (bf16x8)0;
        float s = 0.f;
        if (p < N_TOT) {
            const float* base = w + (size_t)p * C_IN + lane * 8;
            f32x4 a = nt_load4(base);
            f32x4 c = nt_load4(base + 4);
            s = a[0]*a[0] + a[1]*a[1] + a[2]*a[2] + a[3]*a[3]
              + c[0]*c[0] + c[1]*c[1] + c[2]*c[2] + c[3]*c[3];
            o[0] = (short)f2bf(a[0]); o[1] = (short)f2bf(a[1]);
            o[2] = (short)f2bf(a[2]); o[3] = (short)f2bf(a[3]);
            o[4] = (short)f2bf(c[0]); o[5] = (short)f2bf(c[1]);
            o[6] = (short)f2bf(c[2]); o[7] = (short)f2bf(c[3]);
        }
        *(bf16x8*)(Wbf + (size_t)p * C_IN + lane * 8) = o;
#pragma unroll
        for (int off = 32; off; off >>= 1) s += __shfl_down(s, off);
        if (lane == 0) w2[p] = s;
        return;
    }

    const int q = t & 15;
    const int part = t >> 4;
    const int m0q = blockIdx.x * 64 + q * 4;
    const uint32_t b  = (uint32_t)m0q / 784u;
    const uint32_t hw = (uint32_t)m0q % 784u;
    const float* base = in + (size_t)b * IMG_STRIDE + hw;

    float acx = 0.f, acy = 0.f, acz = 0.f, acw = 0.f;
    const int c0 = part * 32;
#pragma unroll 4
    for (int c = c0; c < c0 + 32; ++c) {
        f32x4 v = nt_load4(base + (size_t)c * HW);
        acx = fmaf(v[0], v[0], acx);
        acy = fmaf(v[1], v[1], acy);
        acz = fmaf(v[2], v[2], acz);
        acw = fmaf(v[3], v[3], acw);
        uint16_t vals[4] = { f2bf(v[0]), f2bf(v[1]), f2bf(v[2]), f2bf(v[3]) };
        const uint32_t by0 = (uint32_t)(q * 4) * 1024u + (uint32_t)c * 2u;
#pragma unroll
        for (int j = 0; j < 4; ++j) {
            uint32_t bb = by0 + (uint32_t)j * 1024u;
            bb ^= ((bb >> 12) & 7u) << 4;
            *(uint16_t*)(T + bb) = vals[j];
        }
    }
    red[part][q * 4 + 0] = acx;
    red[part][q * 4 + 1] = acy;
    red[part][q * 4 + 2] = acz;
    red[part][q * 4 + 3] = acw;
    __syncthreads();
    if (t < 64) {
        float s = 0.f;
#pragma unroll
        for (int p = 0; p < 16; ++p) s += red[p][t];
        s2[blockIdx.x * 64 + t] = s;
    }
    short* dst = Abf + (size_t)blockIdx.x * 64 * 512;
#pragma unroll
    for (int i = 0; i < 16; ++i) {
        const int idx = i * 256 + t;
        const int row = idx >> 6, ch = idx & 63;
        uint32_t bb = (uint32_t)row * 1024u + (uint32_t)ch * 16u;
        bb ^= ((bb >> 12) & 7u) << 4;
        bf16x8 v = *(bf16x8*)(T + bb);
        *(bf16x8*)(dst + (size_t)row * 512 + ch * 8) = v;
    }
}

// ---------------------------------------------------------------------------
// gemm13: gemm9's proven loop (256x128 block, 4 waves of 128x64, BK=32,
// ring-3 LDS 72 KB -> 2 blocks/CU, single barrier + counted vmcnt(6) per
// K-tile, measured-0-conflict slot swizzle) + XCD-LOCALITY REMAP:
//   xcd = bid&7;  L = xcd*196 + (bid>>3);  bm = L>>4;  bn = L&15   (bijective)
// Each XCD owns a contiguous ~12-bm run, bn-fast inside: its 64 resident
// blocks span ~4 A-panels (1 MB) + 16 B-panels (2 MB) = 3 MB < 4 MB L2, so
// staging reads L2-hit instead of escaping to L3/HBM (round-9 FETCH=108 MB).
__global__ __launch_bounds__(256, 2) void gemm13_kernel(const short* __restrict__ Abf,
                                                        const short* __restrict__ Wbf,
                                                        const float* __restrict__ s2,
                                                        const float* __restrict__ w2,
                                                        float* __restrict__ out) {
    __shared__ __align__(16) char smem[3 * 24576];   // 72 KB

    const int t = threadIdx.x;
    const int wv = t >> 6, lane = t & 63;
    const int lr = lane & 15, lg = lane >> 4;

    // XCD-locality mapping (assumes round-robin bid->XCD; if mapping differs
    // this is only a locality heuristic, never a correctness issue)
    const int bid = blockIdx.x;
    const int L  = (bid & 7) * 196 + (bid >> 3);
    const int bm = L >> 4;               // 0..97
    const int bn = L & 15;               // 0..15

    const short* Ap = Abf + (size_t)bm * TBM * C_IN;
    const short* Bp = Wbf + (size_t)bn * TBN * C_IN;

    // ---- staging: instr j dest = buf + jbase + t*16
    //      -> row = jrow + wv*16 + (lane>>2), storage slot = lane&3
    //      source logical k-group = (lane&3) ^ ((row>>1)&3) = (lane&3)^((lane>>3)&3)
    const int srow = wv * 16 + (lane >> 2);
    const int sg   = (lane & 3) ^ ((lane >> 3) & 3);
    const short* AsrcL = Ap + (size_t)srow * C_IN + sg * 8;   // + j*64 rows
    const short* BsrcL = Bp + (size_t)srow * C_IN + sg * 8;   // + j*64 rows
    const int dst = t * 16;

    // ---- wave -> output subtile (128m x 64n)
    const int wm = (wv >> 1) * 128;        // {0,128}
    const int wn = (wv & 1) * 64;          // {0,64}

    // ---- ds_read: row r at 64 B stride, slot lg^((lr>>1)&3)
    const int slot  = lg ^ ((lr >> 1) & 3);
    const int abase = (wm + lr) * 64 + slot * 16;            // + m*1024
    const int bbase = 16384 + (wn + lr) * 64 + slot * 16;    // + n*1024

    f32x4 acc[8][4] = {};

#define STAGE(tt)                                                              \
    do {                                                                       \
        char* buf_ = smem + ((tt) % 3) * 24576;                                \
        const short* as_ = AsrcL + (tt) * 32;                                  \
        const short* bs_ = BsrcL + (tt) * 32;                                  \
        gload_lds16(as_,              buf_ + dst);                             \
        gload_lds16(as_ +  64 * C_IN, buf_ + 4096 + dst);                      \
        gload_lds16(as_ + 128 * C_IN, buf_ + 8192 + dst);                      \
        gload_lds16(as_ + 192 * C_IN, buf_ + 12288 + dst);                     \
        gload_lds16(bs_,              buf_ + 16384 + dst);                     \
        gload_lds16(bs_ +  64 * C_IN, buf_ + 20480 + dst);                     \
    } while (0)

    // prologue: issue stages for tiles 0,1 (12 loads in flight)
    STAGE(0);
    STAGE(1);

#pragma unroll
    for (int kt = 0; kt < NKT; ++kt) {
        // entry gate: my stage(kt) landed; stage(kt+1)'s 6 stay in flight
        if (kt < NKT - 1) asm volatile("s_waitcnt vmcnt(6)" ::: "memory");
        else              asm volatile("s_waitcnt vmcnt(0)" ::: "memory");
        __builtin_amdgcn_sched_barrier(0);
        __builtin_amdgcn_s_barrier();      // all waves' stage(kt) landed;
        __builtin_amdgcn_sched_barrier(0); // buf (kt+2)%3 fully consumed (iter kt-1)

        if (kt + 2 < NKT) STAGE(kt + 2);   // into buffer freed at this barrier

        const char* buf = smem + (kt % 3) * 24576;
        bf16x8 bfrag[4], afrag[8];
#pragma unroll
        for (int n = 0; n < 4; ++n)
            bfrag[n] = *(const bf16x8*)(buf + bbase + n * 1024);
#pragma unroll
        for (int m = 0; m < 8; ++m)
            afrag[m] = *(const bf16x8*)(buf + abase + m * 1024);

        __builtin_amdgcn_s_setprio(1);
#pragma unroll
        for (int m = 0; m < 8; ++m)
#pragma unroll
            for (int n = 0; n < 4; ++n)
                acc[m][n] = __builtin_amdgcn_mfma_f32_16x16x32_bf16(
                    afrag[m], bfrag[n], acc[m][n], 0, 0, 0);
        __builtin_amdgcn_s_setprio(0);
    }
#undef STAGE

    // epilogue: relu(s2 - 2*acc + w2), regular f32x4 stores (nt hurt: r13)
    float wreg[4];
    int n_ok[4];
#pragma unroll
    for (int n = 0; n < 4; ++n) {
        const int n_o = bn * TBN + wn + n * 16 + lr;
        n_ok[n] = (n_o < N_TOT);
        wreg[n] = n_ok[n] ? w2[n_o] : 0.f;
    }
#pragma unroll
    for (int m = 0; m < 8; ++m) {
        const int m_r = bm * TBM + wm + m * 16 + lg * 4;   // 4-aligned, 784%4==0
        const f32x4 s2v = *(const f32x4*)(s2 + m_r);
        const uint32_t ob  = (uint32_t)m_r / 784u;
        const uint32_t ohw = (uint32_t)m_r % 784u;
        float* obase = out + (size_t)ob * OUT_BATCH + ohw;
#pragma unroll
        for (int n = 0; n < 4; ++n) {
            if (n_ok[n]) {
                const int n_o = bn * TBN + wn + n * 16 + lr;
                const f32x4 a = acc[m][n];
                f32x4 r;
                r[0] = fmaxf(s2v[0] - 2.f * a[0] + wreg[n], 0.f);
                r[1] = fmaxf(s2v[1] - 2.f * a[1] + wreg[n], 0.f);
                r[2] = fmaxf(s2v[2] - 2.f * a[2] + wreg[n], 0.f);
                r[3] = fmaxf(s2v[3] - 2.f * a[3] + wreg[n], 0.f);
                *(f32x4*)(obase + (size_t)n_o * HW) = r;
            }
        }
    }
}

// ---------------------------------------------------------------------------
extern "C" void kernel_launch(void* const* d_in, const int* in_sizes, int n_in,
                              void* d_out, int out_size, void* d_ws, size_t ws_size,
                              hipStream_t stream) {
    const float* in = (const float*)d_in[0];   // [32,512,28,28] fp32
    const float* w  = (const float*)d_in[1];   // [2000,512,1,1] fp32
    float* out = (float*)d_out;                // [32,2000,28,28] fp32

    const size_t offA  = 0;
    const size_t offW  = offA + (size_t)M_TOT * C_IN * sizeof(short);   // 25.7 MB
    const size_t offS2 = offW + (size_t)NPAD * C_IN * sizeof(short);    // +2.1 MB
    const size_t offW2 = offS2 + (size_t)M_TOT * sizeof(float);

    short* Abf = (short*)((char*)d_ws + offA);
    short* Wbf = (short*)((char*)d_ws + offW);
    float* s2  = (float*)((char*)d_ws + offS2);
    float* w2  = (float*)((char*)d_ws + offW2);

    prep_kernel<<<PREPA_BLOCKS + PREPW_BLOCKS, 256, 0, stream>>>(in, w, Abf, Wbf, s2, w2);

    // 98 m-tiles x 16 n-tiles = 1568 blocks, 2 resident per CU (3.06 rounds)
    gemm13_kernel<<<98 * 16, 256, 0, stream>>>(Abf, Wbf, s2, w2, out);
}